// Round 11
// baseline (348.177 us; speedup 1.0000x reference)
//
#include <hip/hip_runtime.h>

// ---------------------------------------------------------------------------
// FeaturePropagationLayer (PointNet++ FP): 3-NN interp -> concat -> MLP(384->256)
// -> GN(32)+ReLU -> MLP(256->128) -> GN(32)+ReLU.  Output (B,N,128).
//
// Round 12: gemm1 occupancy via smaller LDS footprint.
//  - gemm1: 32-query blocks (A panel 24K resident) + 2 column passes of 128
//    cols (B tile 16K, restaged; W re-reads are L2-resident).  LDS = 40960 B
//    exactly -> 4 blocks/CU -> 32 waves/CU for the gather prologue (R7-interp
//    occupancy) while keeping 8-wave barrier groups (R9's 16-wave convoy
//    avoided).  Per-wave tile 16x32, acc 8 VGPR, __launch_bounds__(512,8).
//  - knn / prep / gemm2 / norm frozen from R10 (verified).
// ---------------------------------------------------------------------------

#define DEVI __device__ __forceinline__

static constexpr int B  = 8;
static constexpr int N  = 8192;
static constexpr int M  = 2048;
static constexpr int C1 = 128;
static constexpr int C2 = 256;
static constexpr int CIN = C1 + C2;   // 384
static constexpr int H0 = 256;
static constexpr int H1 = 128;
static constexpr int BN = B * N;      // 65536
static constexpr int NSEG = 8;        // knn M-split
static constexpr int SEGL = M / NSEG; // 256

typedef __bf16 bf16x8 __attribute__((ext_vector_type(8)));
typedef float  f32x4  __attribute__((ext_vector_type(4)));
typedef unsigned short ushort8v __attribute__((ext_vector_type(8)));

DEVI float bf2f(unsigned short u) {
    union { unsigned int i; float f; } v; v.i = ((unsigned int)u) << 16; return v.f;
}
DEVI unsigned short f2bf(float f) {
    union { float f; unsigned int i; } v; v.f = f;
    unsigned int x = v.i;
    return (unsigned short)((x + 0x7fffu + ((x >> 16) & 1u)) >> 16);
}
DEVI float ldin(const void* p, size_t i, int bf) {
    return bf ? bf2f(((const unsigned short*)p)[i]) : ((const float*)p)[i];
}
DEVI void ld8(const void* p, size_t i, int bf, float r[8]) {
    if (bf) {
        const ushort8v u = *(const ushort8v*)((const unsigned short*)p + i);
#pragma unroll
        for (int k = 0; k < 8; k++) r[k] = bf2f(u[k]);
    } else {
        const float4 a = *(const float4*)((const float*)p + i);
        const float4 b = *(const float4*)((const float*)p + i + 4);
        r[0] = a.x; r[1] = a.y; r[2] = a.z; r[3] = a.w;
        r[4] = b.x; r[5] = b.y; r[6] = b.z; r[7] = b.w;
    }
}
// 8 bf16 -> float[8]
DEVI void ld8b(const unsigned short* p, size_t i, float r[8]) {
    const ushort8v u = *(const ushort8v*)(p + i);
#pragma unroll
    for (int k = 0; k < 8; k++) r[k] = bf2f(u[k]);
}

// Inline wave-uniform dtype detect (validated R9/R10).
DEVI int detect_bf(const void* xyz1) {
    const unsigned short* u = (const unsigned short*)xyz1;
    const int lane = threadIdx.x & 63;
    const float av = fabsf(bf2f(u[2 * lane]));
    const bool in_range = (av >= 1e-4f && av <= 100.0f);
    const unsigned long long m = __ballot(in_range);
    return (__popcll(m) >= 32) ? 1 : 0;
}

DEVI void gload16(const void* g, void* l) {
    __builtin_amdgcn_global_load_lds(
        (const __attribute__((address_space(1))) void*)g,
        (__attribute__((address_space(3))) void*)l, 16, 0, 0);
}

// ---------------------------------------------------------------------------
// K0: prep — w0/w1/p2 -> bf16; xyz2 -> float4(x,y,z,0.5|p|^2); zero parts.
// (frozen)
// ---------------------------------------------------------------------------
DEVI void cvt8(const void* src, unsigned short* dst, size_t j8, int bf) {
    if (bf) {
        *(ushort8v*)(dst + j8 * 8) = *(const ushort8v*)((const unsigned short*)src + j8 * 8);
    } else {
        float r[8];
        ld8(src, j8 * 8, 0, r);
        ushort8v o;
#pragma unroll
        for (int k = 0; k < 8; k++) o[k] = f2bf(r[k]);
        *(ushort8v*)(dst + j8 * 8) = o;
    }
}

__global__ __launch_bounds__(256) void prep_kernel(
    const void* __restrict__ w0, const void* __restrict__ w1,
    const void* __restrict__ p2,
    const void* __restrict__ xyz1, const void* __restrict__ xyz2,
    unsigned short* __restrict__ w0b, unsigned short* __restrict__ w1b,
    unsigned short* __restrict__ pb2,
    float4* __restrict__ c4, float* __restrict__ partz)
{
    const int bf = detect_bf(xyz1);
    constexpr int R0 = H0 * CIN / 8;        // 12288
    constexpr int R1 = H1 * H0 / 8;         // 4096
    constexpr int R2 = B * M;               // 16384 (scalar, c4)
    constexpr int R4 = B * M * C2 / 8;      // 524288
    constexpr int R5 = 1024;                // part floats
    constexpr int TOT = R0 + R1 + R2 + R4 + R5;
    for (int i = blockIdx.x * blockDim.x + threadIdx.x; i < TOT; i += gridDim.x * blockDim.x) {
        int j = i;
        if (j < R0) { cvt8(w0, w0b, j, bf); continue; }
        j -= R0;
        if (j < R1) { cvt8(w1, w1b, j, bf); continue; }
        j -= R1;
        if (j < R2) {
            const float x = ldin(xyz2, (size_t)j * 3 + 0, bf);
            const float y = ldin(xyz2, (size_t)j * 3 + 1, bf);
            const float z = ldin(xyz2, (size_t)j * 3 + 2, bf);
            const float sq = __fadd_rn(__fadd_rn(__fmul_rn(x, x), __fmul_rn(y, y)), __fmul_rn(z, z));
            c4[j] = make_float4(x, y, z, 0.5f * sq);
            continue;
        }
        j -= R2;
        if (j < R4) { cvt8(p2, pb2, j, bf); continue; }
        j -= R4;
        partz[j] = 0.f;
    }
}

// ---------------------------------------------------------------------------
// K1: 3-NN search, M split 8-way, dual insert chains (frozen, verified).
// ---------------------------------------------------------------------------
__global__ __launch_bounds__(256) void knn3_split_kernel(
    const void* __restrict__ xyz1, const float4* __restrict__ c4,
    int* __restrict__ ci)
{
    const int bf = detect_bf(xyz1);
    const int tid = threadIdx.x;
    const int gid = blockIdx.x * 256 + tid;        // b*N + n
    const int s = blockIdx.y;                      // 0..NSEG-1
    const int b = __builtin_amdgcn_readfirstlane(gid >> 13);

    const float x1 = ldin(xyz1, (size_t)gid * 3 + 0, bf);
    const float y1 = ldin(xyz1, (size_t)gid * 3 + 1, bf);
    const float z1 = ldin(xyz1, (size_t)gid * 3 + 2, bf);

    const float4* __restrict__ cand = c4 + b * M + s * SEGL;
    const int jbase = s * SEGL;
    constexpr int HALF = SEGL / 2;                 // 128

    float a0 = 3.4e38f, a1 = 3.4e38f, a2 = 3.4e38f;
    int   ia0 = 0, ia1 = 0, ia2 = 0;
    float g0 = 3.4e38f, g1 = 3.4e38f, g2 = 3.4e38f;
    int   ig0 = 0, ig1 = 0, ig2 = 0;

#pragma unroll 4
    for (int j = 0; j < HALF; ++j) {
        const float4 pA = cand[j];
        const float4 pB = cand[j + HALF];
        const float sA = __builtin_fmaf(-x1, pA.x,
                          __builtin_fmaf(-y1, pA.y,
                           __builtin_fmaf(-z1, pA.z, pA.w)));
        const float sB = __builtin_fmaf(-x1, pB.x,
                          __builtin_fmaf(-y1, pB.y,
                           __builtin_fmaf(-z1, pB.z, pB.w)));
        {   // chain A
            const int jn = jbase + j;
            const bool c0 = sA < a0;
            const float t1 = fmaxf(sA, a0); a0 = fminf(sA, a0);
            const int  tj1 = c0 ? ia0 : jn; ia0 = c0 ? jn : ia0;
            const bool c1 = t1 < a1;
            const float t2 = fmaxf(t1, a1); a1 = fminf(t1, a1);
            const int  tj2 = c1 ? ia1 : tj1; ia1 = c1 ? tj1 : ia1;
            const bool c2 = t2 < a2;
            a2 = fminf(t2, a2); ia2 = c2 ? tj2 : ia2;
        }
        {   // chain B
            const int jn = jbase + HALF + j;
            const bool c0 = sB < g0;
            const float t1 = fmaxf(sB, g0); g0 = fminf(sB, g0);
            const int  tj1 = c0 ? ig0 : jn; ig0 = c0 ? jn : ig0;
            const bool c1 = t1 < g1;
            const float t2 = fmaxf(t1, g1); g1 = fminf(t1, g1);
            const int  tj2 = c1 ? ig1 : tj1; ig1 = c1 ? tj1 : ig1;
            const bool c2 = t2 < g2;
            g2 = fminf(t2, g2); ig2 = c2 ? tj2 : ig2;
        }
    }

    float mv[3] = { g0, g1, g2 };
    int   mi[3] = { ig0, ig1, ig2 };
#pragma unroll
    for (int k = 0; k < 3; ++k) {
        const float sv = mv[k]; const int jn = mi[k];
        const bool c0 = sv < a0;
        const float t1 = fmaxf(sv, a0); a0 = fminf(sv, a0);
        const int  tj1 = c0 ? ia0 : jn; ia0 = c0 ? jn : ia0;
        const bool c1 = t1 < a1;
        const float t2 = fmaxf(t1, a1); a1 = fminf(t1, a1);
        const int  tj2 = c1 ? ia1 : tj1; ia1 = c1 ? tj1 : ia1;
        const bool c2 = t2 < a2;
        a2 = fminf(t2, a2); ia2 = c2 ? tj2 : ia2;
    }

    ci[(size_t)(s * 3 + 0) * BN + gid] = ia0;
    ci[(size_t)(s * 3 + 1) * BN + gid] = ia1;
    ci[(size_t)(s * 3 + 2) * BN + gid] = ia2;
}

// ---------------------------------------------------------------------------
// K2: GEMM1 fused with merge+interp.  h0(BN,256) = interp_concat @ W0^T.
// 32-query block, 512 threads (8 waves 2x4), A panel 24K resident, B 16K
// streamed in 2 column passes of 128.  LDS 40960 -> 4 blocks/CU.
// ---------------------------------------------------------------------------
__global__ __launch_bounds__(512, 8) void gemm1_kernel(
    const void* __restrict__ p1, const unsigned short* __restrict__ pb2,
    const void* __restrict__ xyz1, const float4* __restrict__ c4,
    const int* __restrict__ ci,
    const unsigned short* __restrict__ W,
    unsigned short* __restrict__ h0, float2* __restrict__ part)
{
    constexpr int K = CIN;            // 384
    constexpr int COUT = H0;          // 256
    // A panel 32x384 bf16 = 24576 @0 | B tile 128x64 bf16 = 16384 @24576
    // prologue scratch aliases B region (dead before first B stage):
    //   dd f32[32][24] @24576 | di i32[32][24] @27648
    //   sidx i32[32][3] @30720 | sw f32[32][3] @31104
    __shared__ __align__(16) char lds[40960];

    const int bf = detect_bf(xyz1);
    const int t = threadIdx.x;
    const int l = t & 63;
    const int w = t >> 6;             // 0..7
    const int qbase = blockIdx.x * 32;
    const int b = qbase >> 13;

    float* dd = (float*)(lds + 24576);
    int*   di = (int*)(lds + 27648);
    int*   sidx = (int*)(lds + 30720);
    float* sw = (float*)(lds + 31104);

    // ---- phase 0: evaluate 24 survivors per query (8 threads/query) ----
    if (t < 256) {
        const int ql = t >> 3;                     // 0..31
        const int q  = qbase + ql;
        const int kk0 = (t & 7) * 3;
        const float x1 = ldin(xyz1, (size_t)q * 3 + 0, bf);
        const float y1 = ldin(xyz1, (size_t)q * 3 + 1, bf);
        const float z1 = ldin(xyz1, (size_t)q * 3 + 2, bf);
        const float sq1 = __fadd_rn(__fadd_rn(__fmul_rn(x1, x1), __fmul_rn(y1, y1)), __fmul_rn(z1, z1));
#pragma unroll
        for (int u = 0; u < 3; ++u) {
            const int k = kk0 + u;
            const int ix = ci[(size_t)k * BN + q];
            const float4 p = c4[b * M + ix];
            const float inner = __fadd_rn(__fadd_rn(__fmul_rn(x1, p.x), __fmul_rn(y1, p.y)),
                                          __fmul_rn(z1, p.z));
            const float pw2 = p.w + p.w;           // exact: 0.5*sq * 2
            const float d = __fadd_rn(__fsub_rn(sq1, __fmul_rn(2.0f, inner)), pw2);
            dd[ql * 24 + k] = d;
            di[ql * 24 + k] = ix;
        }
    }
    __syncthreads();

    // ---- phase 1: per-query (d,idx) tie-broken top-3 + weights ----
    if (t < 32) {
        float bd0 = 3.4e38f, bd1 = 3.4e38f, bd2 = 3.4e38f;
        int   bi0 = 0x7fffffff, bi1 = 0x7fffffff, bi2 = 0x7fffffff;
#pragma unroll
        for (int k = 0; k < 24; ++k) {
            const float d  = dd[t * 24 + k];
            const int   ix = di[t * 24 + k];
            const bool lt2 = (d < bd2) || (d == bd2 && ix < bi2);
            if (lt2) {
                const bool lt0 = (d < bd0) || (d == bd0 && ix < bi0);
                const bool lt1 = (d < bd1) || (d == bd1 && ix < bi1);
                if (lt0)      { bd2 = bd1; bi2 = bi1; bd1 = bd0; bi1 = bi0; bd0 = d; bi0 = ix; }
                else if (lt1) { bd2 = bd1; bi2 = bi1; bd1 = d; bi1 = ix; }
                else          { bd2 = d; bi2 = ix; }
            }
        }
        const float v0 = 1.0f / (bd0 + 1e-8f);
        const float v1 = 1.0f / (bd1 + 1e-8f);
        const float v2 = 1.0f / (bd2 + 1e-8f);
        const float s = v0 + v1 + v2;
        sidx[t * 3 + 0] = bi0; sidx[t * 3 + 1] = bi1; sidx[t * 3 + 2] = bi2;
        sw[t * 3 + 0] = v0 / s; sw[t * 3 + 1] = v1 / s; sw[t * 3 + 2] = v2 / s;
    }
    __syncthreads();

    // ---- phase 2: interp+concat -> A panel (swizzled ds_write) ----
#pragma unroll 1
    for (int it = 0; it < 3; ++it) {
        const int task = it * 512 + t;             // 0..1535
        const int ql = task / 48;                  // 0..31
        const int c8 = task % 48;
        const int c  = c8 * 8;
        float v[8];
        if (c < C1) {
            ld8(p1, (size_t)(qbase + ql) * C1 + c, bf, v);
        } else {
            const int c2 = c - C1;
            float t0[8], t1[8], t2[8];
            ld8b(pb2, (size_t)(b * M + sidx[ql * 3 + 0]) * C2 + c2, t0);
            ld8b(pb2, (size_t)(b * M + sidx[ql * 3 + 1]) * C2 + c2, t1);
            ld8b(pb2, (size_t)(b * M + sidx[ql * 3 + 2]) * C2 + c2, t2);
            const float w0v = sw[ql * 3 + 0], w1v = sw[ql * 3 + 1], w2v = sw[ql * 3 + 2];
#pragma unroll
            for (int k = 0; k < 8; k++) v[k] = w0v * t0[k] + w1v * t1[k] + w2v * t2[k];
        }
        ushort8v o;
#pragma unroll
        for (int k = 0; k < 8; k++) o[k] = f2bf(v[k]);
        *(ushort8v*)(lds + ql * 768 + ((c8 >> 3) << 7) + ((((c8 & 7) ^ (ql & 7)) << 4))) = o;
    }
    __syncthreads();

    // ---- K-loop: 2 column passes; stream B, MFMA against resident A ----
    const int srow  = l >> 3;
    const int sslot = l & 7;
    const int wr  = w >> 2;           // 0..1 (16-row strip)
    const int wc  = w & 3;            // 0..3 (32-col strip within pass)
    const int rl  = l & 15;
    const int kq  = l >> 4;
    const int swz7 = l & 7;

    const int aoff = (wr * 16 + rl) * 768;
    int boff[2];
#pragma unroll
    for (int j = 0; j < 2; j++) boff[j] = 24576 + (wc * 32 + j * 16 + rl) * 128;

    constexpr int NT = K / 64;        // 6

#pragma unroll 1
    for (int cp = 0; cp < 2; ++cp) {
        f32x4 acc[2];
        acc[0] = (f32x4)0.0f; acc[1] = (f32x4)0.0f;

#pragma unroll 1
        for (int tt = 0; tt < NT; ++tt) {
            const int k0 = tt * 64;
#pragma unroll
            for (int i = 0; i < 2; ++i) {
                const int cb = w * 2 + i;                 // 0..15
                const int rb = cb * 8 + srow;             // 0..127
                const int ke = (sslot ^ (rb & 7)) << 3;
                gload16(W + ((size_t)(cp * 128 + rb) * K + k0 + ke),
                        lds + 24576 + cb * 1024);
            }
            __syncthreads();
#pragma unroll
            for (int ks = 0; ks < 2; ++ks) {
                const int akb = (tt << 7) + (((ks * 4 + kq) ^ swz7) << 4);
                const int bkb = (ks * 64 + kq * 16) ^ (swz7 << 4);
                const bf16x8 af = *(const bf16x8*)(lds + aoff + akb);
                bf16x8 bfr[2];
#pragma unroll
                for (int j = 0; j < 2; j++) bfr[j] = *(const bf16x8*)(lds + boff[j] + bkb);
#pragma unroll
                for (int j = 0; j < 2; j++)
                    acc[j] = __builtin_amdgcn_mfma_f32_16x16x32_bf16(af, bfr[j], acc[j], 0, 0, 0);
            }
            __syncthreads();
        }

        // ---- epilogue for this pass: h0 store + GN0 stats (cpg=8) ----
        const int crow = qbase + wr * 16 + kq * 4;
        float gsum[2], gss[2];
#pragma unroll
        for (int j = 0; j < 2; j++) {
            float s = 0.f, ss = 0.f;
#pragma unroll
            for (int r = 0; r < 4; r++) {
                const unsigned short hb = f2bf(acc[j][r]);
                h0[(size_t)(crow + r) * COUT + cp * 128 + wc * 32 + j * 16 + rl] = hb;
                const float x = bf2f(hb);
                s += x; ss += x * x;
            }
            gsum[j] = s; gss[j] = ss;
        }
        // B region is dead after the pass's last K-step sync; use as sred.
        float2* sred = (float2*)(lds + 24576);
        if (t < 32) sred[t] = make_float2(0.f, 0.f);
        __syncthreads();
#pragma unroll
        for (int j = 0; j < 2; j++) {
            const int g = cp * 16 + wc * 4 + j * 2 + (rl >> 3);   // col>>3, cpg=8
            atomicAdd(&sred[g].x, gsum[j]);
            atomicAdd(&sred[g].y, gss[j]);
        }
        __syncthreads();
        if (t < 32) {
            atomicAdd(&part[b * 32 + t].x, sred[t].x);
            atomicAdd(&part[b * 32 + t].y, sred[t].y);
        }
        __syncthreads();              // protect sred before next pass stages B
    }
}

// ---------------------------------------------------------------------------
// K3: GEMM2 fused.  h1(BN,128) = relu(gn0(h0)) @ W1^T.  64-row tile, 256
// threads (4 waves 2x2 of 32x64), LDS 24KB.  (frozen from R10)
// ---------------------------------------------------------------------------
__global__ __launch_bounds__(256) void gemm2_kernel(
    const unsigned short* __restrict__ h0, const float2* __restrict__ part0,
    const void* __restrict__ gw, const void* __restrict__ gb,
    const unsigned short* __restrict__ W, const void* __restrict__ xyz1,
    unsigned short* __restrict__ h1, float2* __restrict__ part1)
{
    constexpr int K = H0;             // 256
    constexpr int COUT = H1;          // 128
    __shared__ __align__(16) char lds[24576];   // A 8K @0 | B 16K @8192
    __shared__ float2 stlds[32];

    const int bf = detect_bf(xyz1);
    const int tid = threadIdx.x;
    const int l   = tid & 63;
    const int w   = tid >> 6;         // 0..3
    const int rowBase = blockIdx.x * 64;
    const int b = rowBase >> 13;

    if (tid < 32) {
        const float2 p = part0[b * 32 + tid];
        const float cnt = (float)N * 8.0f;          // cpg=8
        const float mu  = p.x / cnt;
        const float var = p.y / cnt - mu * mu;
        stlds[tid] = make_float2(mu, rsqrtf(var + 1e-5f));
    }
    __syncthreads();

    const int srow  = l >> 3;
    const int sslot = l & 7;

    f32x4 acc[2][4];
#pragma unroll
    for (int i = 0; i < 2; i++)
#pragma unroll
        for (int j = 0; j < 4; j++) acc[i][j] = (f32x4)0.0f;

    const int wr  = (tid >> 7) & 1;   // 0..1: 32-row strip
    const int wc  = (tid >> 6) & 1;   // 0..1: 64-col strip
    const int rl  = l & 15;
    const int kq  = l >> 4;
    const int swz = (l & 7) << 4;
    int aoff[2], boff[4];
#pragma unroll
    for (int i = 0; i < 2; i++) aoff[i] = (wr * 32 + i * 16 + rl) * 128;
#pragma unroll
    for (int j = 0; j < 4; j++) boff[j] = 8192 + (wc * 64 + j * 16 + rl) * 128;

    constexpr int NT = K / 64;        // 4

#pragma unroll 1
    for (int t = 0; t < NT; ++t) {
        const int k0 = t * 64;
#pragma unroll
        for (int i = 0; i < 4; ++i) {
            const int cb = w * 4 + i;                 // 0..15
            const int r  = cb * 8 + srow;             // 0..127
            const int ke = (sslot ^ (r & 7)) << 3;
            gload16(W + ((size_t)r * K + k0 + ke), lds + 8192 + cb * 1024);
        }
#pragma unroll
        for (int i = 0; i < 2; ++i) {
            const int r = (w * 2 + i) * 8 + srow;     // 0..63
            const int kslot = sslot ^ (r & 7);
            const int c = k0 + (kslot << 3);          // 8 ch, one group (cpg=8)
            const float2 ms = stlds[c >> 3];
            float gwv[8], gbv[8];
            ld8(gw, c, bf, gwv);
            ld8(gb, c, bf, gbv);
            const ushort8v hv = *(const ushort8v*)(h0 + (size_t)(rowBase + r) * H0 + c);
            ushort8v o;
#pragma unroll
            for (int k = 0; k < 8; k++) {
                const float x = bf2f(hv[k]);
                o[k] = f2bf(fmaxf((x - ms.x) * ms.y * gwv[k] + gbv[k], 0.f));
            }
            *(ushort8v*)(lds + r * 128 + (sslot << 4)) = o;
        }
        __syncthreads();
#pragma unroll
        for (int ks = 0; ks < 2; ++ks) {
            const int kb = (ks * 64 + kq * 16) ^ swz;
            bf16x8 af[2], bfr[4];
#pragma unroll
            for (int i = 0; i < 2; i++) af[i]  = *(const bf16x8*)(lds + aoff[i] + kb);
#pragma unroll
            for (int j = 0; j < 4; j++) bfr[j] = *(const bf16x8*)(lds + boff[j] + kb);
#pragma unroll
            for (int i = 0; i < 2; i++)
#pragma unroll
                for (int j = 0; j < 4; j++)
                    acc[i][j] = __builtin_amdgcn_mfma_f32_16x16x32_bf16(af[i], bfr[j], acc[i][j], 0, 0, 0);
        }
        __syncthreads();
    }

    // ---- epilogue: h1 store + GN1 stats (cpg=4) ----
    const int crow = rowBase + wr * 32 + kq * 4;
    const int ccol = wc * 64 + rl;
    float gsum[4], gss[4];
#pragma unroll
    for (int j = 0; j < 4; j++) {
        float s = 0.f, ss = 0.f;
#pragma unroll
        for (int i = 0; i < 2; i++)
#pragma unroll
            for (int r = 0; r < 4; r++) {
                const unsigned short hb = f2bf(acc[i][j][r]);
                h1[(size_t)(crow + i * 16 + r) * COUT + ccol + j * 16] = hb;
                const float x = bf2f(hb);
                s += x; ss += x * x;
            }
        gsum[j] = s; gss[j] = ss;
    }
    __syncthreads();
    float2* sred = (float2*)lds;
    if (tid < 32) sred[tid] = make_float2(0.f, 0.f);
    __syncthreads();
#pragma unroll
    for (int j = 0; j < 4; j++) {
        const int g = wc * 16 + j * 4 + (rl >> 2);   // col>>2, cpg=4
        atomicAdd(&sred[g].x, gsum[j]);
        atomicAdd(&sred[g].y, gss[j]);
    }
    __syncthreads();
    if (tid < 32) {
        atomicAdd(&part1[b * 32 + tid].x, sred[tid].x);
        atomicAdd(&part1[b * 32 + tid].y, sred[tid].y);
    }
}

// ---------------------------------------------------------------------------
// K4: final normalize + affine + ReLU on bf16 h1 -> d_out.  (frozen)
// ---------------------------------------------------------------------------
__global__ __launch_bounds__(256) void gn_norm_relu_kernel(
    const unsigned short* __restrict__ h, const float2* __restrict__ part1,
    const void* __restrict__ gw, const void* __restrict__ gb,
    const void* __restrict__ xyz1, void* __restrict__ out)
{
    constexpr int C = H1;            // 128
    constexpr int cpg = 4;
    constexpr int C4 = C >> 2;
    constexpr int total4 = BN * C / 4;

    __shared__ float2 stlds[256];
    {
        const float2 p = part1[threadIdx.x];        // 256 == B*32
        const float cnt = (float)N * (float)cpg;
        const float mu  = p.x / cnt;
        const float var = p.y / cnt - mu * mu;
        stlds[threadIdx.x] = make_float2(mu, rsqrtf(var + 1e-5f));
    }
    const int bf = detect_bf(xyz1);
    __syncthreads();

    for (int i4 = blockIdx.x * blockDim.x + threadIdx.x; i4 < total4; i4 += gridDim.x * blockDim.x) {
        const int c = (i4 % C4) * 4;
        const int p = i4 / C4;
        const int b = p >> 13;
        const float2 ms = stlds[b * 32 + c / cpg];
        const ushort4 hv = *(const ushort4*)(h + (size_t)i4 * 4);
        float r[4] = { bf2f(hv.x), bf2f(hv.y), bf2f(hv.z), bf2f(hv.w) };
#pragma unroll
        for (int k = 0; k < 4; k++) {
            const float gwv = ldin(gw, c + k, bf);
            const float gbv = ldin(gb, c + k, bf);
            r[k] = fmaxf((r[k] - ms.x) * ms.y * gwv + gbv, 0.f);
        }
        if (bf) {
            ushort4 o;
            o.x = f2bf(r[0]); o.y = f2bf(r[1]); o.z = f2bf(r[2]); o.w = f2bf(r[3]);
            *(ushort4*)((unsigned short*)out + (size_t)i4 * 4) = o;
        } else {
            float4 o; o.x = r[0]; o.y = r[1]; o.z = r[2]; o.w = r[3];
            *(float4*)((float*)out + (size_t)i4 * 4) = o;
        }
    }
}

// ---------------------------------------------------------------------------
extern "C" void kernel_launch(void* const* d_in, const int* in_sizes, int n_in,
                              void* d_out, int out_size, void* d_ws, size_t ws_size,
                              hipStream_t stream)
{
    const void* xyz1    = d_in[0];
    const void* xyz2    = d_in[1];
    const void* points1 = d_in[2];
    const void* points2 = d_in[3];
    const void* w0      = d_in[4];
    const void* w1      = d_in[5];
    const void* gn0w    = d_in[6];
    const void* gn0b    = d_in[7];
    const void* gn1w    = d_in[8];
    const void* gn1b    = d_in[9];

    char* ws = (char*)d_ws;
    // layout (bytes):
    //         0  h0     bf16 BN*256*2 = 33554432
    //  33554432  h1     bf16 BN*128*2 = 16777216
    //  50331648  w0b    196608
    //  50528256  w1b    65536
    //  50593792  pb2    bf16 B*M*256*2 = 8388608
    //  58982400  c4     B*M*16 = 262144
    //  59244544  ci     BN*24*4 = 6291456
    //  65536000  part0  2048   (part0+part1 contiguous: zeroed as 1024 floats)
    //  65538048  part1  2048
    unsigned short* h0     = (unsigned short*)ws;
    unsigned short* h1     = (unsigned short*)(ws + 33554432);
    unsigned short* w0b    = (unsigned short*)(ws + 50331648);
    unsigned short* w1b    = (unsigned short*)(ws + 50528256);
    unsigned short* pb2    = (unsigned short*)(ws + 50593792);
    float4*         c4     = (float4*)(ws + 58982400);
    int*            ci     = (int*)(ws + 59244544);
    float2*         part0  = (float2*)(ws + 65536000);
    float2*         part1  = (float2*)(ws + 65538048);

    prep_kernel<<<1024, 256, 0, stream>>>(w0, w1, points2, xyz1, xyz2,
                                          w0b, w1b, pb2, c4, (float*)part0);

    {
        dim3 g(BN / 256, NSEG);   // (256, 8)
        knn3_split_kernel<<<g, 256, 0, stream>>>(xyz1, c4, ci);
    }

    gemm1_kernel<<<BN / 32, 512, 0, stream>>>(points1, pb2, xyz1, c4, ci,
                                              w0b, h0, part0);

    gemm2_kernel<<<BN / 64, 256, 0, stream>>>(h0, part0, gn0w, gn0b, w1b, xyz1,
                                              h1, part1);

    gn_norm_relu_kernel<<<2048, 256, 0, stream>>>(h1, part1, gn1w, gn1b, xyz1, d_out);
}

// Round 12
// 292.770 us; speedup vs baseline: 1.1892x; 1.1892x over previous
//
#include <hip/hip_runtime.h>

// ---------------------------------------------------------------------------
// FeaturePropagationLayer (PointNet++ FP): 3-NN interp -> concat -> MLP(384->256)
// -> GN(32)+ReLU -> MLP(256->128) -> GN(32)+ReLU.  Output (B,N,128).
//
// Round 13: consolidation at the measured optimum (R8 = 294.1 us config).
//  - gemm1: R8's fused merge+interp GEMM (512 thr, 64-row block, A-panel
//    resident, pb2 bf16 gathers, full 256-col B stream).  Measured 87-89 us
//    twice (R8, R10).  Occupancy experiments R9/R11 both regressed ->
//    this config is the empirical optimum of the structure.
//  - gemm2: R8's 128-row version (in the 294.1 measurement).
//  - norm: R8's grid-1024 version.
//  - Only delta vs R8: detect kernel folded inline (validated R9-R11).
// ---------------------------------------------------------------------------

#define DEVI __device__ __forceinline__

static constexpr int B  = 8;
static constexpr int N  = 8192;
static constexpr int M  = 2048;
static constexpr int C1 = 128;
static constexpr int C2 = 256;
static constexpr int CIN = C1 + C2;   // 384
static constexpr int H0 = 256;
static constexpr int H1 = 128;
static constexpr int BN = B * N;      // 65536
static constexpr int NSEG = 8;        // knn M-split
static constexpr int SEGL = M / NSEG; // 256

typedef __bf16 bf16x8 __attribute__((ext_vector_type(8)));
typedef float  f32x4  __attribute__((ext_vector_type(4)));
typedef unsigned short ushort8v __attribute__((ext_vector_type(8)));

DEVI float bf2f(unsigned short u) {
    union { unsigned int i; float f; } v; v.i = ((unsigned int)u) << 16; return v.f;
}
DEVI unsigned short f2bf(float f) {
    union { float f; unsigned int i; } v; v.f = f;
    unsigned int x = v.i;
    return (unsigned short)((x + 0x7fffu + ((x >> 16) & 1u)) >> 16);
}
DEVI float ldin(const void* p, size_t i, int bf) {
    return bf ? bf2f(((const unsigned short*)p)[i]) : ((const float*)p)[i];
}
DEVI void ld8(const void* p, size_t i, int bf, float r[8]) {
    if (bf) {
        const ushort8v u = *(const ushort8v*)((const unsigned short*)p + i);
#pragma unroll
        for (int k = 0; k < 8; k++) r[k] = bf2f(u[k]);
    } else {
        const float4 a = *(const float4*)((const float*)p + i);
        const float4 b = *(const float4*)((const float*)p + i + 4);
        r[0] = a.x; r[1] = a.y; r[2] = a.z; r[3] = a.w;
        r[4] = b.x; r[5] = b.y; r[6] = b.z; r[7] = b.w;
    }
}
// 8 bf16 -> float[8]
DEVI void ld8b(const unsigned short* p, size_t i, float r[8]) {
    const ushort8v u = *(const ushort8v*)(p + i);
#pragma unroll
    for (int k = 0; k < 8; k++) r[k] = bf2f(u[k]);
}

// Inline wave-uniform dtype detect (validated R9-R11).
DEVI int detect_bf(const void* xyz1) {
    const unsigned short* u = (const unsigned short*)xyz1;
    const int lane = threadIdx.x & 63;
    const float av = fabsf(bf2f(u[2 * lane]));
    const bool in_range = (av >= 1e-4f && av <= 100.0f);
    const unsigned long long m = __ballot(in_range);
    return (__popcll(m) >= 32) ? 1 : 0;
}

DEVI void gload16(const void* g, void* l) {
    __builtin_amdgcn_global_load_lds(
        (const __attribute__((address_space(1))) void*)g,
        (__attribute__((address_space(3))) void*)l, 16, 0, 0);
}

// ---------------------------------------------------------------------------
// K0: prep — w0/w1/p2 -> bf16; xyz2 -> float4(x,y,z,0.5|p|^2); zero parts.
// ---------------------------------------------------------------------------
DEVI void cvt8(const void* src, unsigned short* dst, size_t j8, int bf) {
    if (bf) {
        *(ushort8v*)(dst + j8 * 8) = *(const ushort8v*)((const unsigned short*)src + j8 * 8);
    } else {
        float r[8];
        ld8(src, j8 * 8, 0, r);
        ushort8v o;
#pragma unroll
        for (int k = 0; k < 8; k++) o[k] = f2bf(r[k]);
        *(ushort8v*)(dst + j8 * 8) = o;
    }
}

__global__ __launch_bounds__(256) void prep_kernel(
    const void* __restrict__ w0, const void* __restrict__ w1,
    const void* __restrict__ p2,
    const void* __restrict__ xyz1, const void* __restrict__ xyz2,
    unsigned short* __restrict__ w0b, unsigned short* __restrict__ w1b,
    unsigned short* __restrict__ pb2,
    float4* __restrict__ c4, float* __restrict__ partz)
{
    const int bf = detect_bf(xyz1);
    constexpr int R0 = H0 * CIN / 8;        // 12288
    constexpr int R1 = H1 * H0 / 8;         // 4096
    constexpr int R2 = B * M;               // 16384 (scalar, c4)
    constexpr int R4 = B * M * C2 / 8;      // 524288
    constexpr int R5 = 1024;                // part floats
    constexpr int TOT = R0 + R1 + R2 + R4 + R5;
    for (int i = blockIdx.x * blockDim.x + threadIdx.x; i < TOT; i += gridDim.x * blockDim.x) {
        int j = i;
        if (j < R0) { cvt8(w0, w0b, j, bf); continue; }
        j -= R0;
        if (j < R1) { cvt8(w1, w1b, j, bf); continue; }
        j -= R1;
        if (j < R2) {
            const float x = ldin(xyz2, (size_t)j * 3 + 0, bf);
            const float y = ldin(xyz2, (size_t)j * 3 + 1, bf);
            const float z = ldin(xyz2, (size_t)j * 3 + 2, bf);
            const float sq = __fadd_rn(__fadd_rn(__fmul_rn(x, x), __fmul_rn(y, y)), __fmul_rn(z, z));
            c4[j] = make_float4(x, y, z, 0.5f * sq);
            continue;
        }
        j -= R2;
        if (j < R4) { cvt8(p2, pb2, j, bf); continue; }
        j -= R4;
        partz[j] = 0.f;
    }
}

// ---------------------------------------------------------------------------
// K1: 3-NN search, M split 8-way, dual insert chains (frozen, verified).
// ---------------------------------------------------------------------------
__global__ __launch_bounds__(256) void knn3_split_kernel(
    const void* __restrict__ xyz1, const float4* __restrict__ c4,
    int* __restrict__ ci)
{
    const int bf = detect_bf(xyz1);
    const int tid = threadIdx.x;
    const int gid = blockIdx.x * 256 + tid;        // b*N + n
    const int s = blockIdx.y;                      // 0..NSEG-1
    const int b = __builtin_amdgcn_readfirstlane(gid >> 13);

    const float x1 = ldin(xyz1, (size_t)gid * 3 + 0, bf);
    const float y1 = ldin(xyz1, (size_t)gid * 3 + 1, bf);
    const float z1 = ldin(xyz1, (size_t)gid * 3 + 2, bf);

    const float4* __restrict__ cand = c4 + b * M + s * SEGL;
    const int jbase = s * SEGL;
    constexpr int HALF = SEGL / 2;                 // 128

    float a0 = 3.4e38f, a1 = 3.4e38f, a2 = 3.4e38f;
    int   ia0 = 0, ia1 = 0, ia2 = 0;
    float g0 = 3.4e38f, g1 = 3.4e38f, g2 = 3.4e38f;
    int   ig0 = 0, ig1 = 0, ig2 = 0;

#pragma unroll 4
    for (int j = 0; j < HALF; ++j) {
        const float4 pA = cand[j];
        const float4 pB = cand[j + HALF];
        const float sA = __builtin_fmaf(-x1, pA.x,
                          __builtin_fmaf(-y1, pA.y,
                           __builtin_fmaf(-z1, pA.z, pA.w)));
        const float sB = __builtin_fmaf(-x1, pB.x,
                          __builtin_fmaf(-y1, pB.y,
                           __builtin_fmaf(-z1, pB.z, pB.w)));
        {   // chain A
            const int jn = jbase + j;
            const bool c0 = sA < a0;
            const float t1 = fmaxf(sA, a0); a0 = fminf(sA, a0);
            const int  tj1 = c0 ? ia0 : jn; ia0 = c0 ? jn : ia0;
            const bool c1 = t1 < a1;
            const float t2 = fmaxf(t1, a1); a1 = fminf(t1, a1);
            const int  tj2 = c1 ? ia1 : tj1; ia1 = c1 ? tj1 : ia1;
            const bool c2 = t2 < a2;
            a2 = fminf(t2, a2); ia2 = c2 ? tj2 : ia2;
        }
        {   // chain B
            const int jn = jbase + HALF + j;
            const bool c0 = sB < g0;
            const float t1 = fmaxf(sB, g0); g0 = fminf(sB, g0);
            const int  tj1 = c0 ? ig0 : jn; ig0 = c0 ? jn : ig0;
            const bool c1 = t1 < g1;
            const float t2 = fmaxf(t1, g1); g1 = fminf(t1, g1);
            const int  tj2 = c1 ? ig1 : tj1; ig1 = c1 ? tj1 : ig1;
            const bool c2 = t2 < g2;
            g2 = fminf(t2, g2); ig2 = c2 ? tj2 : ig2;
        }
    }

    float mv[3] = { g0, g1, g2 };
    int   mi[3] = { ig0, ig1, ig2 };
#pragma unroll
    for (int k = 0; k < 3; ++k) {
        const float sv = mv[k]; const int jn = mi[k];
        const bool c0 = sv < a0;
        const float t1 = fmaxf(sv, a0); a0 = fminf(sv, a0);
        const int  tj1 = c0 ? ia0 : jn; ia0 = c0 ? jn : ia0;
        const bool c1 = t1 < a1;
        const float t2 = fmaxf(t1, a1); a1 = fminf(t1, a1);
        const int  tj2 = c1 ? ia1 : tj1; ia1 = c1 ? tj1 : ia1;
        const bool c2 = t2 < a2;
        a2 = fminf(t2, a2); ia2 = c2 ? tj2 : ia2;
    }

    ci[(size_t)(s * 3 + 0) * BN + gid] = ia0;
    ci[(size_t)(s * 3 + 1) * BN + gid] = ia1;
    ci[(size_t)(s * 3 + 2) * BN + gid] = ia2;
}

// ---------------------------------------------------------------------------
// K2: GEMM1 fused with merge+interp (R8 config, measured 87-89us twice).
// h0(BN,256) = interp_concat @ W0^T.  64-row block, 512 threads (8 waves 2x4),
// full-K A-panel resident in LDS; pb2 bf16 gathers.
// ---------------------------------------------------------------------------
__global__ __launch_bounds__(512, 4) void gemm1_kernel(
    const void* __restrict__ p1, const unsigned short* __restrict__ pb2,
    const void* __restrict__ xyz1, const float4* __restrict__ c4,
    const int* __restrict__ ci,
    const unsigned short* __restrict__ W,
    unsigned short* __restrict__ h0, float2* __restrict__ part)
{
    constexpr int K = CIN;            // 384
    constexpr int COUT = H0;          // 256
    __shared__ __align__(16) char lds[81920];   // A 48K @0 | B 32K @49152 (scratch-shared)

    const int bf = detect_bf(xyz1);
    const int t = threadIdx.x;
    const int l = t & 63;
    const int w = t >> 6;             // 0..7
    const int qbase = blockIdx.x * 64;
    const int b = qbase >> 13;

    float* dd = (float*)(lds + 49152);
    int*   di = (int*)(lds + 55296);
    int*   sidx = (int*)(lds + 61440);
    float* sw = (float*)(lds + 62208);

    // ---- phase 0: evaluate 24 survivors per query (8 threads/query) ----
    {
        const int ql = t >> 3;                     // 0..63
        const int q  = qbase + ql;
        const int kk0 = (t & 7) * 3;
        const float x1 = ldin(xyz1, (size_t)q * 3 + 0, bf);
        const float y1 = ldin(xyz1, (size_t)q * 3 + 1, bf);
        const float z1 = ldin(xyz1, (size_t)q * 3 + 2, bf);
        const float sq1 = __fadd_rn(__fadd_rn(__fmul_rn(x1, x1), __fmul_rn(y1, y1)), __fmul_rn(z1, z1));
#pragma unroll
        for (int u = 0; u < 3; ++u) {
            const int k = kk0 + u;
            const int ix = ci[(size_t)k * BN + q];
            const float4 p = c4[b * M + ix];
            const float inner = __fadd_rn(__fadd_rn(__fmul_rn(x1, p.x), __fmul_rn(y1, p.y)),
                                          __fmul_rn(z1, p.z));
            const float pw2 = p.w + p.w;           // exact: 0.5*sq * 2
            const float d = __fadd_rn(__fsub_rn(sq1, __fmul_rn(2.0f, inner)), pw2);
            dd[ql * 24 + k] = d;
            di[ql * 24 + k] = ix;
        }
    }
    __syncthreads();

    // ---- phase 1: per-query (d,idx) tie-broken top-3 + weights ----
    if (t < 64) {
        float bd0 = 3.4e38f, bd1 = 3.4e38f, bd2 = 3.4e38f;
        int   bi0 = 0x7fffffff, bi1 = 0x7fffffff, bi2 = 0x7fffffff;
#pragma unroll
        for (int k = 0; k < 24; ++k) {
            const float d  = dd[t * 24 + k];
            const int   ix = di[t * 24 + k];
            const bool lt2 = (d < bd2) || (d == bd2 && ix < bi2);
            if (lt2) {
                const bool lt0 = (d < bd0) || (d == bd0 && ix < bi0);
                const bool lt1 = (d < bd1) || (d == bd1 && ix < bi1);
                if (lt0)      { bd2 = bd1; bi2 = bi1; bd1 = bd0; bi1 = bi0; bd0 = d; bi0 = ix; }
                else if (lt1) { bd2 = bd1; bi2 = bi1; bd1 = d; bi1 = ix; }
                else          { bd2 = d; bi2 = ix; }
            }
        }
        const float v0 = 1.0f / (bd0 + 1e-8f);
        const float v1 = 1.0f / (bd1 + 1e-8f);
        const float v2 = 1.0f / (bd2 + 1e-8f);
        const float s = v0 + v1 + v2;
        sidx[t * 3 + 0] = bi0; sidx[t * 3 + 1] = bi1; sidx[t * 3 + 2] = bi2;
        sw[t * 3 + 0] = v0 / s; sw[t * 3 + 1] = v1 / s; sw[t * 3 + 2] = v2 / s;
    }
    __syncthreads();

    // ---- phase 2: interp+concat -> A panel (swizzled ds_write) ----
#pragma unroll 1
    for (int it = 0; it < 6; ++it) {
        const int task = it * 512 + t;             // 0..3071
        const int ql = task / 48;                  // 0..63
        const int c8 = task % 48;
        const int c  = c8 * 8;
        float v[8];
        if (c < C1) {
            ld8(p1, (size_t)(qbase + ql) * C1 + c, bf, v);
        } else {
            const int c2 = c - C1;
            float t0[8], t1[8], t2[8];
            ld8b(pb2, (size_t)(b * M + sidx[ql * 3 + 0]) * C2 + c2, t0);
            ld8b(pb2, (size_t)(b * M + sidx[ql * 3 + 1]) * C2 + c2, t1);
            ld8b(pb2, (size_t)(b * M + sidx[ql * 3 + 2]) * C2 + c2, t2);
            const float w0v = sw[ql * 3 + 0], w1v = sw[ql * 3 + 1], w2v = sw[ql * 3 + 2];
#pragma unroll
            for (int k = 0; k < 8; k++) v[k] = w0v * t0[k] + w1v * t1[k] + w2v * t2[k];
        }
        ushort8v o;
#pragma unroll
        for (int k = 0; k < 8; k++) o[k] = f2bf(v[k]);
        *(ushort8v*)(lds + ql * 768 + ((c8 >> 3) << 7) + ((((c8 & 7) ^ (ql & 7)) << 4))) = o;
    }
    __syncthreads();

    // ---- K-loop: stream B, MFMA against resident A ----
    const int srow  = l >> 3;
    const int sslot = l & 7;
    const int wr  = w >> 2;           // 0..1
    const int wc  = w & 3;            // 0..3
    const int rl  = l & 15;
    const int kq  = l >> 4;
    const int swz7 = l & 7;

    f32x4 acc[2][4];
#pragma unroll
    for (int i = 0; i < 2; i++)
#pragma unroll
        for (int j = 0; j < 4; j++) acc[i][j] = (f32x4)0.0f;

    int aoff[2], boff[4];
#pragma unroll
    for (int i = 0; i < 2; i++) aoff[i] = (wr * 32 + i * 16 + rl) * 768;
#pragma unroll
    for (int j = 0; j < 4; j++) boff[j] = 49152 + (wc * 64 + j * 16 + rl) * 128;

    constexpr int NT = K / 64;        // 6

#pragma unroll 1
    for (int tt = 0; tt < NT; ++tt) {
        const int k0 = tt * 64;
#pragma unroll
        for (int i = 0; i < 4; ++i) {
            const int cb = w * 4 + i;                 // 0..31
            const int rb = cb * 8 + srow;             // 0..255
            const int ke = (sslot ^ (rb & 7)) << 3;
            gload16(W + ((size_t)rb * K + k0 + ke), lds + 49152 + cb * 1024);
        }
        __syncthreads();
#pragma unroll
        for (int ks = 0; ks < 2; ++ks) {
            const int akb = (tt << 7) + (((ks * 4 + kq) ^ swz7) << 4);
            const int bkb = (ks * 64 + kq * 16) ^ (swz7 << 4);
            bf16x8 af[2], bfr[4];
#pragma unroll
            for (int i = 0; i < 2; i++) af[i]  = *(const bf16x8*)(lds + aoff[i] + akb);
#pragma unroll
            for (int j = 0; j < 4; j++) bfr[j] = *(const bf16x8*)(lds + boff[j] + bkb);
#pragma unroll
            for (int i = 0; i < 2; i++)
#pragma unroll
                for (int j = 0; j < 4; j++)
                    acc[i][j] = __builtin_amdgcn_mfma_f32_16x16x32_bf16(af[i], bfr[j], acc[i][j], 0, 0, 0);
        }
        __syncthreads();
    }

    // ---- epilogue: h0 store + GN0 stats (cpg=8) ----
    const int crow = qbase + wr * 32 + kq * 4;
    const int ccol = wc * 64 + rl;
    float gsum[4], gss[4];
#pragma unroll
    for (int j = 0; j < 4; j++) {
        float s = 0.f, ss = 0.f;
#pragma unroll
        for (int i = 0; i < 2; i++)
#pragma unroll
            for (int r = 0; r < 4; r++) {
                const unsigned short hb = f2bf(acc[i][j][r]);
                h0[(size_t)(crow + i * 16 + r) * COUT + ccol + j * 16] = hb;
                const float x = bf2f(hb);
                s += x; ss += x * x;
            }
        gsum[j] = s; gss[j] = ss;
    }
    __syncthreads();
    float2* sred = (float2*)lds;           // 32 groups
    if (t < 32) sred[t] = make_float2(0.f, 0.f);
    __syncthreads();
#pragma unroll
    for (int j = 0; j < 4; j++) {
        const int g = wc * 8 + j * 2 + (rl >> 3);    // col>>3, cpg=8
        atomicAdd(&sred[g].x, gsum[j]);
        atomicAdd(&sred[g].y, gss[j]);
    }
    __syncthreads();
    if (t < 32) {
        atomicAdd(&part[b * 32 + t].x, sred[t].x);
        atomicAdd(&part[b * 32 + t].y, sred[t].y);
    }
}

// ---------------------------------------------------------------------------
// K3: GEMM2 fused (R8's 128-row config, in the 294.1 measurement).
// h1(BN,128) = relu(gn0(h0)) @ W1^T.  In-kernel GN0 finalize; GN0 norm+ReLU
// in A-staging; epilogue h1 + GN1 stats (cpg=4).
// ---------------------------------------------------------------------------
__global__ __launch_bounds__(256) void gemm2_kernel(
    const unsigned short* __restrict__ h0, const float2* __restrict__ part0,
    const void* __restrict__ gw, const void* __restrict__ gb,
    const unsigned short* __restrict__ W, const void* __restrict__ xyz1,
    unsigned short* __restrict__ h1, float2* __restrict__ part1)
{
    constexpr int K = H0;             // 256
    constexpr int COUT = H1;          // 128
    __shared__ __align__(16) char lds[32768];   // A 16KB @0 | B 16KB @16384
    __shared__ float2 stlds[32];

    const int bf = detect_bf(xyz1);
    const int tid = threadIdx.x;
    const int l   = tid & 63;
    const int w   = tid >> 6;
    const int rowBase = blockIdx.x * 128;
    const int b = rowBase >> 13;

    if (tid < 32) {
        const float2 p = part0[b * 32 + tid];
        const float cnt = (float)N * 8.0f;          // cpg=8
        const float mu  = p.x / cnt;
        const float var = p.y / cnt - mu * mu;
        stlds[tid] = make_float2(mu, rsqrtf(var + 1e-5f));
    }
    __syncthreads();

    const int srow  = l >> 3;
    const int sslot = l & 7;

    f32x4 acc[4][4];
#pragma unroll
    for (int i = 0; i < 4; i++)
#pragma unroll
        for (int j = 0; j < 4; j++) acc[i][j] = (f32x4)0.0f;

    const int wr  = (tid >> 7) & 1;
    const int wc  = (tid >> 6) & 1;
    const int rl  = l & 15;
    const int kq  = l >> 4;
    const int swz = (l & 7) << 4;
    int aoff[4], boff[4];
#pragma unroll
    for (int i = 0; i < 4; i++) {
        aoff[i] = (wr * 64 + i * 16 + rl) * 128;
        boff[i] = 16384 + (wc * 64 + i * 16 + rl) * 128;
    }

    constexpr int NT = K / 64;        // 4

#pragma unroll 1
    for (int t = 0; t < NT; ++t) {
        const int k0 = t * 64;
#pragma unroll
        for (int i = 0; i < 4; ++i) {
            const int cb = w * 4 + i;                 // 0..15
            const int r  = cb * 8 + srow;             // 0..127
            const int ke = (sslot ^ (r & 7)) << 3;
            gload16(W + ((size_t)r * K + k0 + ke), lds + 16384 + cb * 1024);
        }
#pragma unroll
        for (int i = 0; i < 4; ++i) {
            const int r = (w * 4 + i) * 8 + srow;     // 0..127
            const int kslot = sslot ^ (r & 7);
            const int c = k0 + (kslot << 3);          // 8 ch, one group (cpg=8)
            const float2 ms = stlds[c >> 3];
            float gwv[8], gbv[8];
            ld8(gw, c, bf, gwv);
            ld8(gb, c, bf, gbv);
            const ushort8v hv = *(const ushort8v*)(h0 + (size_t)(rowBase + r) * H0 + c);
            ushort8v o;
#pragma unroll
            for (int k = 0; k < 8; k++) {
                const float x = bf2f(hv[k]);
                o[k] = f2bf(fmaxf((x - ms.x) * ms.y * gwv[k] + gbv[k], 0.f));
            }
            *(ushort8v*)(lds + r * 128 + (sslot << 4)) = o;
        }
        __syncthreads();
#pragma unroll
        for (int ks = 0; ks < 2; ++ks) {
            const int kb = (ks * 64 + kq * 16) ^ swz;
            bf16x8 af[4], bfr[4];
#pragma unroll
            for (int i = 0; i < 4; i++) af[i]  = *(const bf16x8*)(lds + aoff[i] + kb);
#pragma unroll
            for (int j = 0; j < 4; j++) bfr[j] = *(const bf16x8*)(lds + boff[j] + kb);
#pragma unroll
            for (int i = 0; i < 4; i++)
#pragma unroll
                for (int j = 0; j < 4; j++)
                    acc[i][j] = __builtin_amdgcn_mfma_f32_16x16x32_bf16(af[i], bfr[j], acc[i][j], 0, 0, 0);
        }
        __syncthreads();
    }

    const int crow = rowBase + wr * 64 + kq * 4;
    const int ccol = wc * 64 + rl;
    float gsum[4], gss[4];
#pragma unroll
    for (int j = 0; j < 4; j++) {
        float s = 0.f, ss = 0.f;
#pragma unroll
        for (int i = 0; i < 4; i++)
#pragma unroll
            for (int r = 0; r < 4; r++) {
                const unsigned short hb = f2bf(acc[i][j][r]);
                h1[(size_t)(crow + i * 16 + r) * COUT + ccol + j * 16] = hb;
                const float x = bf2f(hb);
                s += x; ss += x * x;
            }
        gsum[j] = s; gss[j] = ss;
    }
    __syncthreads();
    float2* sred = (float2*)lds;
    if (tid < 32) sred[tid] = make_float2(0.f, 0.f);
    __syncthreads();
#pragma unroll
    for (int j = 0; j < 4; j++) {
        const int g = wc * 16 + j * 4 + (rl >> 2);   // col>>2, cpg=4
        atomicAdd(&sred[g].x, gsum[j]);
        atomicAdd(&sred[g].y, gss[j]);
    }
    __syncthreads();
    if (tid < 32) {
        atomicAdd(&part1[b * 32 + tid].x, sred[tid].x);
        atomicAdd(&part1[b * 32 + tid].y, sred[tid].y);
    }
}

// ---------------------------------------------------------------------------
// K4: final normalize + affine + ReLU on bf16 h1 -> d_out (R8 config).
// ---------------------------------------------------------------------------
__global__ __launch_bounds__(256) void gn_norm_relu_kernel(
    const unsigned short* __restrict__ h, const float2* __restrict__ part1,
    const void* __restrict__ gw, const void* __restrict__ gb,
    const void* __restrict__ xyz1, void* __restrict__ out)
{
    constexpr int C = H1;            // 128
    constexpr int cpg = 4;
    constexpr int C4 = C >> 2;
    constexpr int total4 = BN * C / 4;

    __shared__ float2 stlds[256];
    {
        const float2 p = part1[threadIdx.x];        // 256 == B*32
        const float cnt = (float)N * (float)cpg;
        const float mu  = p.x / cnt;
        const float var = p.y / cnt - mu * mu;
        stlds[threadIdx.x] = make_float2(mu, rsqrtf(var + 1e-5f));
    }
    const int bf = detect_bf(xyz1);
    __syncthreads();

    for (int i4 = blockIdx.x * blockDim.x + threadIdx.x; i4 < total4; i4 += gridDim.x * blockDim.x) {
        const int c = (i4 % C4) * 4;
        const int p = i4 / C4;
        const int b = p >> 13;
        const float2 ms = stlds[b * 32 + c / cpg];
        const ushort4 hv = *(const ushort4*)(h + (size_t)i4 * 4);
        float r[4] = { bf2f(hv.x), bf2f(hv.y), bf2f(hv.z), bf2f(hv.w) };
#pragma unroll
        for (int k = 0; k < 4; k++) {
            const float gwv = ldin(gw, c + k, bf);
            const float gbv = ldin(gb, c + k, bf);
            r[k] = fmaxf((r[k] - ms.x) * ms.y * gwv + gbv, 0.f);
        }
        if (bf) {
            ushort4 o;
            o.x = f2bf(r[0]); o.y = f2bf(r[1]); o.z = f2bf(r[2]); o.w = f2bf(r[3]);
            *(ushort4*)((unsigned short*)out + (size_t)i4 * 4) = o;
        } else {
            float4 o; o.x = r[0]; o.y = r[1]; o.z = r[2]; o.w = r[3];
            *(float4*)((float*)out + (size_t)i4 * 4) = o;
        }
    }
}

// ---------------------------------------------------------------------------
extern "C" void kernel_launch(void* const* d_in, const int* in_sizes, int n_in,
                              void* d_out, int out_size, void* d_ws, size_t ws_size,
                              hipStream_t stream)
{
    const void* xyz1    = d_in[0];
    const void* xyz2    = d_in[1];
    const void* points1 = d_in[2];
    const void* points2 = d_in[3];
    const void* w0      = d_in[4];
    const void* w1      = d_in[5];
    const void* gn0w    = d_in[6];
    const void* gn0b    = d_in[7];
    const void* gn1w    = d_in[8];
    const void* gn1b    = d_in[9];

    char* ws = (char*)d_ws;
    // layout (bytes):
    //         0  h0     bf16 BN*256*2 = 33554432
    //  33554432  h1     bf16 BN*128*2 = 16777216
    //  50331648  w0b    196608
    //  50528256  w1b    65536
    //  50593792  pb2    bf16 B*M*256*2 = 8388608
    //  58982400  c4     B*M*16 = 262144
    //  59244544  ci     BN*24*4 = 6291456
    //  65536000  part0  2048   (part0+part1 contiguous: zeroed as 1024 floats)
    //  65538048  part1  2048
    unsigned short* h0     = (unsigned short*)ws;
    unsigned short* h1     = (unsigned short*)(ws + 33554432);
    unsigned short* w0b    = (unsigned short*)(ws + 50331648);
    unsigned short* w1b    = (unsigned short*)(ws + 50528256);
    unsigned short* pb2    = (unsigned short*)(ws + 50593792);
    float4*         c4     = (float4*)(ws + 58982400);
    int*            ci     = (int*)(ws + 59244544);
    float2*         part0  = (float2*)(ws + 65536000);
    float2*         part1  = (float2*)(ws + 65538048);

    prep_kernel<<<1024, 256, 0, stream>>>(w0, w1, points2, xyz1, xyz2,
                                          w0b, w1b, pb2, c4, (float*)part0);

    {
        dim3 g(BN / 256, NSEG);   // (256, 8)
        knn3_split_kernel<<<g, 256, 0, stream>>>(xyz1, c4, ci);
    }

    gemm1_kernel<<<BN / 64, 512, 0, stream>>>(points1, pb2, xyz1, c4, ci,
                                              w0b, h0, part0);

    gemm2_kernel<<<BN / 128, 256, 0, stream>>>(h0, part0, gn0w, gn0b, w1b, xyz1,
                                               h1, part1);

    gn_norm_relu_kernel<<<1024, 256, 0, stream>>>(h1, part1, gn1w, gn1b, xyz1, d_out);
}